// Round 1
// baseline (1067.940 us; speedup 1.0000x reference)
//
#include <hip/hip_runtime.h>
#include <math.h>

// GCN: h = elu(D^-1/2 (A+I) D^-1/2 (h W) + b [+ resid])
// N=100000 nodes, E=1600000 edges, 128 features in/out per layer.
//
// Pipeline per kernel_launch (graph-capture safe, all on `stream`):
//  1. memset cnt=0; count in-degree of dst (int atomics)
//  2. dinv[i] = rsqrt(1 + cnt[i])          (self-loop included)
//  3. exclusive scan cnt -> row_ptr        (single-block scan)
//  4. cursor = row_ptr; CSR fill: col[pos]=src, wgt[pos]=dinv[s]*dinv[d]
//  5. 3x { GEMM (hW = h @ W), aggregate+bias+resid+ELU (pull, no float atomics) }

#define NFEAT 128
#define GEMM_NODES 32  // nodes per block; 100000 % 32 == 0

__global__ __launch_bounds__(256) void count_kernel(
    const int* __restrict__ dst, int* __restrict__ cnt, int e) {
  int i = blockIdx.x * 256 + threadIdx.x;
  if (i < e) atomicAdd(&cnt[dst[i]], 1);
}

__global__ __launch_bounds__(256) void dinv_kernel(
    const int* __restrict__ cnt, float* __restrict__ dinv, int n) {
  int i = blockIdx.x * 256 + threadIdx.x;
  if (i < n) dinv[i] = rsqrtf(1.0f + (float)cnt[i]);
}

// Single-block exclusive scan: row_ptr[0]=0, row_ptr[i+1]=sum cnt[0..i]
__global__ __launch_bounds__(1024) void scan_kernel(
    const int* __restrict__ cnt, int* __restrict__ row_ptr, int n) {
  __shared__ int carry;
  __shared__ int wsum[16];
  int lane = threadIdx.x & 63;
  int wid = threadIdx.x >> 6;
  if (threadIdx.x == 0) { carry = 0; row_ptr[0] = 0; }
  __syncthreads();
  for (int base = 0; base < n; base += 1024) {
    int i = base + (int)threadIdx.x;
    int v = (i < n) ? cnt[i] : 0;
    // inclusive scan within wave (64 lanes)
    int s = v;
    #pragma unroll
    for (int off = 1; off < 64; off <<= 1) {
      int u = __shfl_up(s, off, 64);
      if (lane >= off) s += u;
    }
    if (lane == 63) wsum[wid] = s;
    __syncthreads();
    if (wid == 0 && lane < 16) {
      int ws = wsum[lane];
      #pragma unroll
      for (int off = 1; off < 16; off <<= 1) {
        int u = __shfl_up(ws, off, 16);
        if (lane >= off) ws += u;
      }
      wsum[lane] = ws;
    }
    __syncthreads();
    int add = carry + (wid > 0 ? wsum[wid - 1] : 0);
    if (i < n) row_ptr[i + 1] = add + s;
    __syncthreads();
    if (threadIdx.x == 0) carry += wsum[15];
    __syncthreads();
  }
}

__global__ __launch_bounds__(256) void cursor_kernel(
    const int* __restrict__ row_ptr, int* __restrict__ cursor, int n) {
  int i = blockIdx.x * 256 + threadIdx.x;
  if (i < n) cursor[i] = row_ptr[i];
}

__global__ __launch_bounds__(256) void fill_kernel(
    const int* __restrict__ src, const int* __restrict__ dst,
    const float* __restrict__ dinv, int* __restrict__ cursor,
    int* __restrict__ col, float* __restrict__ wgt, int e) {
  int i = blockIdx.x * 256 + threadIdx.x;
  if (i < e) {
    int s = src[i], d = dst[i];
    int pos = atomicAdd(&cursor[d], 1);
    col[pos] = s;
    wgt[pos] = dinv[s] * dinv[d];
  }
}

// hW[n,128] = h[n,128] @ W[128,128]; W rows streamed from L2, x tile in LDS.
__global__ __launch_bounds__(256) void gemm_kernel(
    const float* __restrict__ h, const float* __restrict__ W,
    float* __restrict__ out) {
  __shared__ float xs[GEMM_NODES * NFEAT];  // 16 KB
  int block0 = blockIdx.x * GEMM_NODES;
  const float4* hsrc = (const float4*)(h + (size_t)block0 * NFEAT);
  float4* xs4 = (float4*)xs;
  #pragma unroll
  for (int i = 0; i < 4; ++i)
    xs4[threadIdx.x + 256 * i] = hsrc[threadIdx.x + 256 * i];
  __syncthreads();

  int fg = threadIdx.x & 31;  // feature group: features [4fg, 4fg+4)
  int ns = threadIdx.x >> 5;  // node slot 0..7; handles nodes ns+8j
  float4 acc[4] = {{0,0,0,0},{0,0,0,0},{0,0,0,0},{0,0,0,0}};
  const float4* W4 = (const float4*)W;
  #pragma unroll 4
  for (int k = 0; k < NFEAT; ++k) {
    float4 w = W4[k * 32 + fg];
    #pragma unroll
    for (int j = 0; j < 4; ++j) {
      float xv = xs[(ns + 8 * j) * NFEAT + k];
      acc[j].x += xv * w.x;
      acc[j].y += xv * w.y;
      acc[j].z += xv * w.z;
      acc[j].w += xv * w.w;
    }
  }
  #pragma unroll
  for (int j = 0; j < 4; ++j) {
    int node = block0 + ns + 8 * j;
    ((float4*)(out + (size_t)node * NFEAT))[fg] = acc[j];
  }
}

// One wave per node: pull in-edges, add self-loop, bias, residual, ELU.
__global__ __launch_bounds__(256) void aggregate_kernel(
    const float* __restrict__ hW, const int* __restrict__ row_ptr,
    const int* __restrict__ col, const float* __restrict__ wgt,
    const float* __restrict__ dinv, const float* __restrict__ bias,
    const float* __restrict__ resid, float* __restrict__ out, int n) {
  int node = (int)((blockIdx.x * 256 + threadIdx.x) >> 6);
  int lane = threadIdx.x & 63;
  if (node >= n) return;
  int beg = row_ptr[node], end = row_ptr[node + 1];
  const float2* hW2 = (const float2*)hW;
  float2 acc = {0.0f, 0.0f};
  for (int e = beg; e < end; ++e) {
    int s = col[e];      // wave-uniform -> broadcast
    float wv = wgt[e];
    float2 v = hW2[(size_t)s * 64 + lane];
    acc.x += wv * v.x;
    acc.y += wv * v.y;
  }
  float di = dinv[node];
  float2 self = hW2[(size_t)node * 64 + lane];
  acc.x += di * di * self.x;
  acc.y += di * di * self.y;
  float2 bv = ((const float2*)bias)[lane];
  acc.x += bv.x;
  acc.y += bv.y;
  if (resid != nullptr) {
    float2 r = ((const float2*)resid)[(size_t)node * 64 + lane];
    acc.x += r.x;
    acc.y += r.y;
  }
  acc.x = acc.x > 0.0f ? acc.x : expm1f(acc.x);
  acc.y = acc.y > 0.0f ? acc.y : expm1f(acc.y);
  ((float2*)out)[(size_t)node * 64 + lane] = acc;
}

extern "C" void kernel_launch(void* const* d_in, const int* in_sizes, int n_in,
                              void* d_out, int out_size, void* d_ws, size_t ws_size,
                              hipStream_t stream) {
  const float* x  = (const float*)d_in[0];
  const int* eidx = (const int*)d_in[1];
  const float* W0 = (const float*)d_in[2];
  const float* b0 = (const float*)d_in[3];
  const float* W1 = (const float*)d_in[4];
  const float* b1 = (const float*)d_in[5];
  const float* W2 = (const float*)d_in[6];
  const float* b2 = (const float*)d_in[7];
  float* outp = (float*)d_out;

  const int N = in_sizes[0] / NFEAT;   // 100000
  const int E = in_sizes[1] / 2;       // 1600000
  const int* src = eidx;
  const int* dst = eidx + E;

  // workspace layout (bytes), all chunks 1KB/16B aligned
  const size_t S1 = 401408;            // > (N+1)*4
  const size_t S2 = 6401024;           // > E*4
  const size_t S3 = (size_t)N * NFEAT * 4;  // 51.2 MB
  char* ws = (char*)d_ws;
  float* dinv   = (float*)(ws);
  int*   cnt    = (int*)(ws + S1);
  int*   rowp   = (int*)(ws + 2 * S1);
  int*   cursor = (int*)(ws + 3 * S1);
  int*   col    = (int*)(ws + 4 * S1);
  float* wgt    = (float*)(ws + 4 * S1 + S2);
  float* hW     = (float*)(ws + 4 * S1 + 2 * S2);
  float* hA     = (float*)(ws + 4 * S1 + 2 * S2 + S3);
  float* hB     = (float*)(ws + 4 * S1 + 2 * S2 + 2 * S3);

  int ge = (E + 255) / 256;
  int gn = (N + 255) / 256;

  // ---- CSR build ----
  hipMemsetAsync(cnt, 0, (size_t)N * 4, stream);
  count_kernel<<<ge, 256, 0, stream>>>(dst, cnt, E);
  dinv_kernel<<<gn, 256, 0, stream>>>(cnt, dinv, N);
  scan_kernel<<<1, 1024, 0, stream>>>(cnt, rowp, N);
  cursor_kernel<<<gn, 256, 0, stream>>>(rowp, cursor, N);
  fill_kernel<<<ge, 256, 0, stream>>>(src, dst, dinv, cursor, col, wgt, E);

  int gemm_blocks = N / GEMM_NODES;        // 3125
  int agg_blocks = (N * 64 + 255) / 256;   // one wave per node

  // ---- layer 0: no residual ----
  gemm_kernel<<<gemm_blocks, 256, 0, stream>>>(x, W0, hW);
  aggregate_kernel<<<agg_blocks, 256, 0, stream>>>(hW, rowp, col, wgt, dinv,
                                                   b0, nullptr, hA, N);
  // ---- layer 1: residual ----
  gemm_kernel<<<gemm_blocks, 256, 0, stream>>>(hA, W1, hW);
  aggregate_kernel<<<agg_blocks, 256, 0, stream>>>(hW, rowp, col, wgt, dinv,
                                                   b1, hA, hB, N);
  // ---- layer 2: residual, write d_out ----
  gemm_kernel<<<gemm_blocks, 256, 0, stream>>>(hB, W2, hW);
  aggregate_kernel<<<agg_blocks, 256, 0, stream>>>(hW, rowp, col, wgt, dinv,
                                                   b2, hB, outp, N);
}

// Round 2
// 681.535 us; speedup vs baseline: 1.5670x; 1.5670x over previous
//
#include <hip/hip_runtime.h>
#include <math.h>

// GCN: h = elu(D^-1/2 (A+I) D^-1/2 (h W) + b [+ resid])
// N=100000 nodes, E=1600000 edges, 128 features per layer.
//
// R2 changes vs R1:
//  - hW stored bf16 (25.6 MB, L3-resident) -> gather bytes halved
//  - aggregate: coalesced col/wgt load + __shfl broadcast, 4 gathers in flight
//  - 3-phase parallel scan replaces single-block serial scan

#define NFEAT 128
#define GEMM_NODES 32  // nodes per block; 100000 % 32 == 0

static __device__ __forceinline__ unsigned short f2bf(float f) {
  union { float f; unsigned int u; } v; v.f = f;
  unsigned int r = v.u + 0x7fffu + ((v.u >> 16) & 1u);  // RNE (finite values)
  return (unsigned short)(r >> 16);
}
static __device__ __forceinline__ float bf2f(unsigned short b) {
  union { unsigned int u; float f; } v; v.u = ((unsigned int)b) << 16;
  return v.f;
}

__global__ __launch_bounds__(256) void count_kernel(
    const int* __restrict__ dst, int* __restrict__ cnt, int e) {
  int i = blockIdx.x * 256 + threadIdx.x;
  if (i < e) atomicAdd(&cnt[dst[i]], 1);
}

// per-block sums of cnt
__global__ __launch_bounds__(256) void partial_kernel(
    const int* __restrict__ cnt, int* __restrict__ bsum, int n) {
  __shared__ int wsum[4];
  int i = blockIdx.x * 256 + threadIdx.x;
  int lane = threadIdx.x & 63, wid = threadIdx.x >> 6;
  int v = (i < n) ? cnt[i] : 0;
  #pragma unroll
  for (int off = 1; off < 64; off <<= 1) v += __shfl_xor(v, off, 64);
  if (lane == 0) wsum[wid] = v;
  __syncthreads();
  if (threadIdx.x == 0)
    bsum[blockIdx.x] = wsum[0] + wsum[1] + wsum[2] + wsum[3];
}

// single-block exclusive scan of block partials (nb <= 512)
__global__ __launch_bounds__(512) void scan_partials_kernel(
    const int* __restrict__ bsum, int* __restrict__ bof,
    int* __restrict__ row_ptr, int nb, int n) {
  __shared__ int wsum[8];
  int t = threadIdx.x, lane = t & 63, wid = t >> 6;
  int v = (t < nb) ? bsum[t] : 0;
  int s = v;
  #pragma unroll
  for (int off = 1; off < 64; off <<= 1) {
    int u = __shfl_up(s, off, 64);
    if (lane >= off) s += u;
  }
  if (lane == 63) wsum[wid] = s;
  __syncthreads();
  int add = 0;
  for (int w = 0; w < wid; ++w) add += wsum[w];
  if (t < nb) bof[t] = add + s - v;
  if (t == 511) row_ptr[n] = add + s;  // grand total == E
}

// exclusive rowptr within each block + fused cursor/dinv init
__global__ __launch_bounds__(256) void rowptr_kernel(
    const int* __restrict__ cnt, const int* __restrict__ bof,
    int* __restrict__ row_ptr, int* __restrict__ cursor,
    float* __restrict__ dinv, int n) {
  __shared__ int wsum[4];
  int i = blockIdx.x * 256 + threadIdx.x;
  int lane = threadIdx.x & 63, wid = threadIdx.x >> 6;
  int v = (i < n) ? cnt[i] : 0;
  int s = v;
  #pragma unroll
  for (int off = 1; off < 64; off <<= 1) {
    int u = __shfl_up(s, off, 64);
    if (lane >= off) s += u;
  }
  if (lane == 63) wsum[wid] = s;
  __syncthreads();
  int add = bof[blockIdx.x];
  for (int w = 0; w < wid; ++w) add += wsum[w];
  if (i < n) {
    int excl = add + s - v;
    row_ptr[i] = excl;
    cursor[i] = excl;
    dinv[i] = rsqrtf(1.0f + (float)v);
  }
}

__global__ __launch_bounds__(256) void fill_kernel(
    const int* __restrict__ src, const int* __restrict__ dst,
    const float* __restrict__ dinv, int* __restrict__ cursor,
    int* __restrict__ col, float* __restrict__ wgt, int e) {
  int i = blockIdx.x * 256 + threadIdx.x;
  if (i < e) {
    int s = src[i], d = dst[i];
    int pos = atomicAdd(&cursor[d], 1);
    col[pos] = s;
    wgt[pos] = dinv[s] * dinv[d];
  }
}

// hW_bf16[n,128] = h[n,128] @ W[128,128]; x tile in LDS, W from L1/L2.
__global__ __launch_bounds__(256) void gemm_kernel(
    const float* __restrict__ h, const float* __restrict__ W,
    unsigned short* __restrict__ out) {
  __shared__ float xs[GEMM_NODES * NFEAT];  // 16 KB
  int block0 = blockIdx.x * GEMM_NODES;
  const float4* hsrc = (const float4*)(h + (size_t)block0 * NFEAT);
  float4* xs4 = (float4*)xs;
  #pragma unroll
  for (int i = 0; i < 4; ++i)
    xs4[threadIdx.x + 256 * i] = hsrc[threadIdx.x + 256 * i];
  __syncthreads();

  int fg = threadIdx.x & 31;  // features [4fg, 4fg+4)
  int ns = threadIdx.x >> 5;  // node slot 0..7; handles nodes ns+8j
  float4 acc[4] = {{0,0,0,0},{0,0,0,0},{0,0,0,0},{0,0,0,0}};
  const float4* W4 = (const float4*)W;
  #pragma unroll 4
  for (int k = 0; k < NFEAT; ++k) {
    float4 w = W4[k * 32 + fg];
    #pragma unroll
    for (int j = 0; j < 4; ++j) {
      float xv = xs[(ns + 8 * j) * NFEAT + k];
      acc[j].x += xv * w.x;
      acc[j].y += xv * w.y;
      acc[j].z += xv * w.z;
      acc[j].w += xv * w.w;
    }
  }
  #pragma unroll
  for (int j = 0; j < 4; ++j) {
    int node = block0 + ns + 8 * j;
    ushort4 o;
    o.x = f2bf(acc[j].x); o.y = f2bf(acc[j].y);
    o.z = f2bf(acc[j].z); o.w = f2bf(acc[j].w);
    ((ushort4*)(out + (size_t)node * NFEAT))[fg] = o;
  }
}

// One wave per node: coalesced col/wgt load, shfl-broadcast, bf16 gather.
__global__ __launch_bounds__(256) void aggregate_kernel(
    const unsigned short* __restrict__ hWb, const int* __restrict__ row_ptr,
    const int* __restrict__ col, const float* __restrict__ wgt,
    const float* __restrict__ dinv, const float* __restrict__ bias,
    const float* __restrict__ resid, float* __restrict__ out, int n) {
  int node = blockIdx.x * 4 + (threadIdx.x >> 6);
  int lane = threadIdx.x & 63;
  if (node >= n) return;
  int beg = row_ptr[node], end = row_ptr[node + 1];
  const ushort2* rows = (const ushort2*)hWb;  // 64 lanes x 2 feats = 256B/row
  float ax = 0.0f, ay = 0.0f;

  for (int cbeg = beg; cbeg < end; cbeg += 64) {
    int cnt = end - cbeg; if (cnt > 64) cnt = 64;
    int cv = 0; float wv = 0.0f;
    if (lane < cnt) { cv = col[cbeg + lane]; wv = wgt[cbeg + lane]; }
    int j = 0;
    for (; j + 4 <= cnt; j += 4) {
      int s0 = __shfl(cv, j + 0, 64), s1 = __shfl(cv, j + 1, 64);
      int s2 = __shfl(cv, j + 2, 64), s3 = __shfl(cv, j + 3, 64);
      float w0 = __shfl(wv, j + 0, 64), w1 = __shfl(wv, j + 1, 64);
      float w2 = __shfl(wv, j + 2, 64), w3 = __shfl(wv, j + 3, 64);
      ushort2 p0 = rows[(size_t)s0 * 64 + lane];
      ushort2 p1 = rows[(size_t)s1 * 64 + lane];
      ushort2 p2 = rows[(size_t)s2 * 64 + lane];
      ushort2 p3 = rows[(size_t)s3 * 64 + lane];
      ax += w0 * bf2f(p0.x); ay += w0 * bf2f(p0.y);
      ax += w1 * bf2f(p1.x); ay += w1 * bf2f(p1.y);
      ax += w2 * bf2f(p2.x); ay += w2 * bf2f(p2.y);
      ax += w3 * bf2f(p3.x); ay += w3 * bf2f(p3.y);
    }
    for (; j < cnt; ++j) {
      int s = __shfl(cv, j, 64);
      float w = __shfl(wv, j, 64);
      ushort2 p = rows[(size_t)s * 64 + lane];
      ax += w * bf2f(p.x); ay += w * bf2f(p.y);
    }
  }

  float di = dinv[node];
  ushort2 ps = rows[(size_t)node * 64 + lane];
  ax += di * di * bf2f(ps.x);
  ay += di * di * bf2f(ps.y);
  float2 bv = ((const float2*)bias)[lane];
  ax += bv.x; ay += bv.y;
  if (resid != nullptr) {
    float2 r = ((const float2*)resid)[(size_t)node * 64 + lane];
    ax += r.x; ay += r.y;
  }
  ax = ax > 0.0f ? ax : expm1f(ax);
  ay = ay > 0.0f ? ay : expm1f(ay);
  float2 o; o.x = ax; o.y = ay;
  ((float2*)out)[(size_t)node * 64 + lane] = o;
}

extern "C" void kernel_launch(void* const* d_in, const int* in_sizes, int n_in,
                              void* d_out, int out_size, void* d_ws, size_t ws_size,
                              hipStream_t stream) {
  const float* x  = (const float*)d_in[0];
  const int* eidx = (const int*)d_in[1];
  const float* W0 = (const float*)d_in[2];
  const float* b0 = (const float*)d_in[3];
  const float* W1 = (const float*)d_in[4];
  const float* b1 = (const float*)d_in[5];
  const float* W2 = (const float*)d_in[6];
  const float* b2 = (const float*)d_in[7];
  float* outp = (float*)d_out;

  const int N = in_sizes[0] / NFEAT;   // 100000
  const int E = in_sizes[1] / 2;       // 1600000
  const int* src = eidx;
  const int* dst = eidx + E;
  const int NB = (N + 255) / 256;      // 391

  // workspace layout (bytes), chunks 1KB-aligned
  const size_t S1 = 401408;                  // > (N+1)*4
  const size_t SB = 4096;                    // > NB*4
  const size_t S2 = 6401024;                 // > E*4
  const size_t S3 = (size_t)N * NFEAT * 4;   // 51.2 MB
  char* ws = (char*)d_ws;
  float* dinv   = (float*)(ws);
  int*   cnt    = (int*)(ws + S1);
  int*   rowp   = (int*)(ws + 2 * S1);
  int*   cursor = (int*)(ws + 3 * S1);
  int*   bsum   = (int*)(ws + 4 * S1);
  int*   bof    = (int*)(ws + 4 * S1 + SB);
  int*   col    = (int*)(ws + 4 * S1 + 2 * SB);
  float* wgt    = (float*)(ws + 4 * S1 + 2 * SB + S2);
  unsigned short* hWb = (unsigned short*)(ws + 4 * S1 + 2 * SB + 2 * S2);
  float* hA     = (float*)(ws + 4 * S1 + 2 * SB + 2 * S2 + S3);  // S3/2 used by hWb, keep gap
  float* hB     = (float*)(ws + 4 * S1 + 2 * SB + 2 * S2 + S3 + S3);

  int ge = (E + 255) / 256;

  // ---- CSR build ----
  hipMemsetAsync(cnt, 0, (size_t)N * 4, stream);
  count_kernel<<<ge, 256, 0, stream>>>(dst, cnt, E);
  partial_kernel<<<NB, 256, 0, stream>>>(cnt, bsum, N);
  scan_partials_kernel<<<1, 512, 0, stream>>>(bsum, bof, rowp, NB, N);
  rowptr_kernel<<<NB, 256, 0, stream>>>(cnt, bof, rowp, cursor, dinv, N);
  fill_kernel<<<ge, 256, 0, stream>>>(src, dst, dinv, cursor, col, wgt, E);

  int gemm_blocks = N / GEMM_NODES;   // 3125
  int agg_blocks = (N + 3) / 4;       // one wave per node

  // ---- layer 0: no residual ----
  gemm_kernel<<<gemm_blocks, 256, 0, stream>>>(x, W0, hWb);
  aggregate_kernel<<<agg_blocks, 256, 0, stream>>>(hWb, rowp, col, wgt, dinv,
                                                   b0, nullptr, hA, N);
  // ---- layer 1: residual ----
  gemm_kernel<<<gemm_blocks, 256, 0, stream>>>(hA, W1, hWb);
  aggregate_kernel<<<agg_blocks, 256, 0, stream>>>(hWb, rowp, col, wgt, dinv,
                                                   b1, hA, hB, N);
  // ---- layer 2: residual, write d_out ----
  gemm_kernel<<<gemm_blocks, 256, 0, stream>>>(hB, W2, hWb);
  aggregate_kernel<<<agg_blocks, 256, 0, stream>>>(hWb, rowp, col, wgt, dinv,
                                                   b2, hB, outp, N);
}

// Round 3
// 593.465 us; speedup vs baseline: 1.7995x; 1.1484x over previous
//
#include <hip/hip_runtime.h>
#include <math.h>

// GCN: h = elu(D^-1/2 (A+I) D^-1/2 (h W) + b [+ resid])
// N=100000 nodes, E=1600000 edges, 128 features per layer.
//
// R3 changes vs R2:
//  - fill: (col,wgt) packed int2, ONE 8B scattered store per edge
//  - GEMM: bf16 MFMA 16x16x32 (operand-swapped -> ushort4 stores),
//    W pre-transposed to bf16 Wt[n][k] by prep kernel
//  - count: int4 edge loads

#define NFEAT 128

typedef short short8 __attribute__((ext_vector_type(8)));
typedef float f32x4 __attribute__((ext_vector_type(4)));

static __device__ __forceinline__ unsigned short f2bf(float f) {
  union { float f; unsigned int u; } v; v.f = f;
  unsigned int r = v.u + 0x7fffu + ((v.u >> 16) & 1u);  // RNE (finite values)
  return (unsigned short)(r >> 16);
}
static __device__ __forceinline__ float bf2f(unsigned short b) {
  union { unsigned int u; float f; } v; v.u = ((unsigned int)b) << 16;
  return v.f;
}
static __device__ __forceinline__ short8 cvt8(float4 a, float4 b) {
  short8 r;
  r[0] = (short)f2bf(a.x); r[1] = (short)f2bf(a.y);
  r[2] = (short)f2bf(a.z); r[3] = (short)f2bf(a.w);
  r[4] = (short)f2bf(b.x); r[5] = (short)f2bf(b.y);
  r[6] = (short)f2bf(b.z); r[7] = (short)f2bf(b.w);
  return r;
}

__global__ __launch_bounds__(256) void count_kernel(
    const int4* __restrict__ dst4, int* __restrict__ cnt, int e4) {
  int i = blockIdx.x * 256 + threadIdx.x;
  if (i < e4) {
    int4 d = dst4[i];
    atomicAdd(&cnt[d.x], 1);
    atomicAdd(&cnt[d.y], 1);
    atomicAdd(&cnt[d.z], 1);
    atomicAdd(&cnt[d.w], 1);
  }
}

// per-block sums of cnt
__global__ __launch_bounds__(256) void partial_kernel(
    const int* __restrict__ cnt, int* __restrict__ bsum, int n) {
  __shared__ int wsum[4];
  int i = blockIdx.x * 256 + threadIdx.x;
  int lane = threadIdx.x & 63, wid = threadIdx.x >> 6;
  int v = (i < n) ? cnt[i] : 0;
  #pragma unroll
  for (int off = 1; off < 64; off <<= 1) v += __shfl_xor(v, off, 64);
  if (lane == 0) wsum[wid] = v;
  __syncthreads();
  if (threadIdx.x == 0)
    bsum[blockIdx.x] = wsum[0] + wsum[1] + wsum[2] + wsum[3];
}

// single-block exclusive scan of block partials (nb <= 512)
__global__ __launch_bounds__(512) void scan_partials_kernel(
    const int* __restrict__ bsum, int* __restrict__ bof,
    int* __restrict__ row_ptr, int nb, int n) {
  __shared__ int wsum[8];
  int t = threadIdx.x, lane = t & 63, wid = t >> 6;
  int v = (t < nb) ? bsum[t] : 0;
  int s = v;
  #pragma unroll
  for (int off = 1; off < 64; off <<= 1) {
    int u = __shfl_up(s, off, 64);
    if (lane >= off) s += u;
  }
  if (lane == 63) wsum[wid] = s;
  __syncthreads();
  int add = 0;
  for (int w = 0; w < wid; ++w) add += wsum[w];
  if (t < nb) bof[t] = add + s - v;
  if (t == 511) row_ptr[n] = add + s;  // grand total == E
}

// exclusive rowptr within each block + fused cursor/dinv init
__global__ __launch_bounds__(256) void rowptr_kernel(
    const int* __restrict__ cnt, const int* __restrict__ bof,
    int* __restrict__ row_ptr, int* __restrict__ cursor,
    float* __restrict__ dinv, int n) {
  __shared__ int wsum[4];
  int i = blockIdx.x * 256 + threadIdx.x;
  int lane = threadIdx.x & 63, wid = threadIdx.x >> 6;
  int v = (i < n) ? cnt[i] : 0;
  int s = v;
  #pragma unroll
  for (int off = 1; off < 64; off <<= 1) {
    int u = __shfl_up(s, off, 64);
    if (lane >= off) s += u;
  }
  if (lane == 63) wsum[wid] = s;
  __syncthreads();
  int add = bof[blockIdx.x];
  for (int w = 0; w < wid; ++w) add += wsum[w];
  if (i < n) {
    int excl = add + s - v;
    row_ptr[i] = excl;
    cursor[i] = excl;
    dinv[i] = rsqrtf(1.0f + (float)v);
  }
}

__global__ __launch_bounds__(256) void fill_kernel(
    const int* __restrict__ src, const int* __restrict__ dst,
    const float* __restrict__ dinv, int* __restrict__ cursor,
    int2* __restrict__ colw, int e) {
  int i = blockIdx.x * 256 + threadIdx.x;
  if (i < e) {
    int s = src[i], d = dst[i];
    int pos = atomicAdd(&cursor[d], 1);
    int2 v;
    v.x = s;
    v.y = __float_as_int(dinv[s] * dinv[d]);
    colw[pos] = v;  // single 8B scattered store
  }
}

// W fp32 [k][n] -> Wt bf16 [n][k]  (128x128), 3 weights in one launch
__global__ __launch_bounds__(256) void wprep_kernel(
    const float* __restrict__ W0, const float* __restrict__ W1,
    const float* __restrict__ W2, unsigned short* __restrict__ Wt0,
    unsigned short* __restrict__ Wt1, unsigned short* __restrict__ Wt2) {
  int which = blockIdx.x >> 6;         // 64 blocks per weight
  int i = (blockIdx.x & 63) * 256 + threadIdx.x;  // 0..16383
  int nn = i >> 7, k = i & 127;        // coalesced 2B writes per n-row
  const float* W = which == 0 ? W0 : (which == 1 ? W1 : W2);
  unsigned short* Wt = which == 0 ? Wt0 : (which == 1 ? Wt1 : Wt2);
  Wt[nn * 128 + k] = f2bf(W[k * 128 + nn]);
}

// hW_bf16[n,128] = h[n,128] @ W via MFMA 16x16x32 bf16.
// Operands swapped (b,a) so D is transposed: lane stores ushort4 runs.
__global__ __launch_bounds__(256) void gemm_mfma_kernel(
    const float* __restrict__ h, const unsigned short* __restrict__ Wt,
    unsigned short* __restrict__ out, int n) {
  int lane = threadIdx.x & 63;
  int wave = threadIdx.x >> 6;
  int row16 = lane & 15;   // node offset within 16 (as B-operand col)
  int kgrp = lane >> 4;    // 0..3
  int node0 = blockIdx.x * 64 + wave * 16;
  int arow = node0 + row16;
  if (arow >= n) arow = n - 1;  // clamp loads; stores guarded

  // h fragments: lane holds h[arow][ks*32 + kgrp*8 + j], j=0..7
  const float4* hrow = (const float4*)(h + (size_t)arow * NFEAT);
  short8 afrag[4];
  #pragma unroll
  for (int ks = 0; ks < 4; ++ks) {
    float4 p0 = hrow[ks * 8 + kgrp * 2];
    float4 p1 = hrow[ks * 8 + kgrp * 2 + 1];
    afrag[ks] = cvt8(p0, p1);
  }

  f32x4 acc[8];
  #pragma unroll
  for (int ct = 0; ct < 8; ++ct) {
    acc[ct] = (f32x4){0.0f, 0.0f, 0.0f, 0.0f};
    // Wt fragment (first operand): lane holds Wt[ct*16+row16][ks*32+kgrp*8+j]
    const short8* wrow =
        (const short8*)(Wt + (size_t)(ct * 16 + row16) * NFEAT);
    #pragma unroll
    for (int ks = 0; ks < 4; ++ks) {
      short8 bfrag = wrow[ks * 4 + kgrp];
      // D' = Wt-rows x h-rows^T -> D'[feat][node]; lane l reg r holds
      // out[node0 + (l&15)][ct*16 + (l>>4)*4 + r]
      acc[ct] = __builtin_amdgcn_mfma_f32_16x16x32_bf16(bfrag, afrag[ks],
                                                        acc[ct], 0, 0, 0);
    }
  }

  int orow = node0 + row16;
  if (orow < n) {
    unsigned short* op = out + (size_t)orow * NFEAT + kgrp * 4;
    #pragma unroll
    for (int ct = 0; ct < 8; ++ct) {
      ushort4 o;
      o.x = f2bf(acc[ct][0]); o.y = f2bf(acc[ct][1]);
      o.z = f2bf(acc[ct][2]); o.w = f2bf(acc[ct][3]);
      *(ushort4*)(op + ct * 16) = o;
    }
  }
}

// One wave per node: coalesced packed-edge load, shfl-broadcast, bf16 gather.
__global__ __launch_bounds__(256) void aggregate_kernel(
    const unsigned short* __restrict__ hWb, const int* __restrict__ row_ptr,
    const int2* __restrict__ colw, const float* __restrict__ dinv,
    const float* __restrict__ bias, const float* __restrict__ resid,
    float* __restrict__ out, int n) {
  int node = blockIdx.x * 4 + (threadIdx.x >> 6);
  int lane = threadIdx.x & 63;
  if (node >= n) return;
  int beg = row_ptr[node], end = row_ptr[node + 1];
  const ushort2* rows = (const ushort2*)hWb;  // 64 lanes x 2 feats = 256B/row
  float ax = 0.0f, ay = 0.0f;

  for (int cbeg = beg; cbeg < end; cbeg += 64) {
    int cnt = end - cbeg; if (cnt > 64) cnt = 64;
    int cv = 0; float wv = 0.0f;
    if (lane < cnt) {
      int2 cw = colw[cbeg + lane];
      cv = cw.x;
      wv = __int_as_float(cw.y);
    }
    int j = 0;
    for (; j + 4 <= cnt; j += 4) {
      int s0 = __shfl(cv, j + 0, 64), s1 = __shfl(cv, j + 1, 64);
      int s2 = __shfl(cv, j + 2, 64), s3 = __shfl(cv, j + 3, 64);
      float w0 = __shfl(wv, j + 0, 64), w1 = __shfl(wv, j + 1, 64);
      float w2 = __shfl(wv, j + 2, 64), w3 = __shfl(wv, j + 3, 64);
      ushort2 p0 = rows[(size_t)s0 * 64 + lane];
      ushort2 p1 = rows[(size_t)s1 * 64 + lane];
      ushort2 p2 = rows[(size_t)s2 * 64 + lane];
      ushort2 p3 = rows[(size_t)s3 * 64 + lane];
      ax += w0 * bf2f(p0.x); ay += w0 * bf2f(p0.y);
      ax += w1 * bf2f(p1.x); ay += w1 * bf2f(p1.y);
      ax += w2 * bf2f(p2.x); ay += w2 * bf2f(p2.y);
      ax += w3 * bf2f(p3.x); ay += w3 * bf2f(p3.y);
    }
    for (; j < cnt; ++j) {
      int s = __shfl(cv, j, 64);
      float w = __shfl(wv, j, 64);
      ushort2 p = rows[(size_t)s * 64 + lane];
      ax += w * bf2f(p.x); ay += w * bf2f(p.y);
    }
  }

  float di = dinv[node];
  ushort2 ps = rows[(size_t)node * 64 + lane];
  ax += di * di * bf2f(ps.x);
  ay += di * di * bf2f(ps.y);
  float2 bv = ((const float2*)bias)[lane];
  ax += bv.x; ay += bv.y;
  if (resid != nullptr) {
    float2 r = ((const float2*)resid)[(size_t)node * 64 + lane];
    ax += r.x; ay += r.y;
  }
  ax = ax > 0.0f ? ax : expm1f(ax);
  ay = ay > 0.0f ? ay : expm1f(ay);
  float2 o; o.x = ax; o.y = ay;
  ((float2*)out)[(size_t)node * 64 + lane] = o;
}

extern "C" void kernel_launch(void* const* d_in, const int* in_sizes, int n_in,
                              void* d_out, int out_size, void* d_ws, size_t ws_size,
                              hipStream_t stream) {
  const float* x  = (const float*)d_in[0];
  const int* eidx = (const int*)d_in[1];
  const float* W0 = (const float*)d_in[2];
  const float* b0 = (const float*)d_in[3];
  const float* W1 = (const float*)d_in[4];
  const float* b1 = (const float*)d_in[5];
  const float* W2 = (const float*)d_in[6];
  const float* b2 = (const float*)d_in[7];
  float* outp = (float*)d_out;

  const int N = in_sizes[0] / NFEAT;   // 100000
  const int E = in_sizes[1] / 2;       // 1600000
  const int* src = eidx;
  const int* dst = eidx + E;
  const int NB = (N + 255) / 256;      // 391

  // workspace layout
  const size_t S1 = 401408;                   // > (N+1)*4
  const size_t SB = 4096;                     // > NB*4
  const size_t SW = 32768;                    // 128*128*2
  const size_t SE = (size_t)E * 8;            // 12.8 MB packed edges
  const size_t SH = (size_t)N * NFEAT * 2;    // 25.6 MB bf16 features
  const size_t SF = (size_t)N * NFEAT * 4;    // 51.2 MB fp32 features
  char* p = (char*)d_ws;
  float* dinv   = (float*)p;            p += S1;
  int*   cnt    = (int*)p;              p += S1;
  int*   rowp   = (int*)p;              p += S1;
  int*   cursor = (int*)p;              p += S1;
  int*   bsum   = (int*)p;              p += SB;
  int*   bof    = (int*)p;              p += SB;
  unsigned short* Wt0 = (unsigned short*)p;  p += SW;
  unsigned short* Wt1 = (unsigned short*)p;  p += SW;
  unsigned short* Wt2 = (unsigned short*)p;  p += SW;
  int2*  colw   = (int2*)p;             p += SE;
  unsigned short* hWb = (unsigned short*)p;  p += SH;
  float* hA     = (float*)p;            p += SF;
  float* hB     = (float*)p;            p += SF;

  int ge = (E + 255) / 256;

  // ---- weight prep (independent of CSR) ----
  wprep_kernel<<<192, 256, 0, stream>>>(W0, W1, W2, Wt0, Wt1, Wt2);

  // ---- CSR build ----
  hipMemsetAsync(cnt, 0, (size_t)N * 4, stream);
  count_kernel<<<(E / 4 + 255) / 256, 256, 0, stream>>>((const int4*)dst, cnt,
                                                        E / 4);
  partial_kernel<<<NB, 256, 0, stream>>>(cnt, bsum, N);
  scan_partials_kernel<<<1, 512, 0, stream>>>(bsum, bof, rowp, NB, N);
  rowptr_kernel<<<NB, 256, 0, stream>>>(cnt, bof, rowp, cursor, dinv, N);
  fill_kernel<<<ge, 256, 0, stream>>>(src, dst, dinv, cursor, colw, E);

  int gemm_blocks = (N + 63) / 64;    // 1563
  int agg_blocks = (N + 3) / 4;       // one wave per node

  // ---- layer 0: no residual ----
  gemm_mfma_kernel<<<gemm_blocks, 256, 0, stream>>>(x, Wt0, hWb, N);
  aggregate_kernel<<<agg_blocks, 256, 0, stream>>>(hWb, rowp, colw, dinv,
                                                   b0, nullptr, hA, N);
  // ---- layer 1: residual ----
  gemm_mfma_kernel<<<gemm_blocks, 256, 0, stream>>>(hA, Wt1, hWb, N);
  aggregate_kernel<<<agg_blocks, 256, 0, stream>>>(hWb, rowp, colw, dinv,
                                                   b1, hA, hB, N);
  // ---- layer 2: residual, write d_out ----
  gemm_mfma_kernel<<<gemm_blocks, 256, 0, stream>>>(hB, Wt2, hWb, N);
  aggregate_kernel<<<agg_blocks, 256, 0, stream>>>(hWb, rowp, colw, dinv,
                                                   b2, hB, outp, N);
}

// Round 5
// 583.298 us; speedup vs baseline: 1.8309x; 1.0174x over previous
//
#include <hip/hip_runtime.h>
#include <math.h>

// GCN: h = elu(D^-1/2 (A+I) D^-1/2 (h W) + b [+ resid])
// N=100000 nodes, E=1600000 edges, 128 features per layer.
//
// R5 = R4 with the remainder-loop fix:
//  - R4 put __shfl inside a divergent branch; ds_bpermute from a lane that
//    is INACTIVE in that branch returns undefined -> dropped edges
//    (absmax 0.179). Now the remainder is branch-free: lanes >= cnt hold
//    (cv,wv)=(0,0) by construction, so shfl'ing them is a harmless w=0 term.
//  - edge record packed to ONE u32: col(17b) | wgt(15b fixed-point)
//  - aggregate: paired gathers (lanes 0-31 edge j, 32-63 edge j+1, ushort4
//    per lane), unroll x4 = 8 edges in flight; shfl_xor(32) combine

#define NFEAT 128

typedef short short8 __attribute__((ext_vector_type(8)));
typedef float f32x4 __attribute__((ext_vector_type(4)));

static __device__ __forceinline__ unsigned short f2bf(float f) {
  union { float f; unsigned int u; } v; v.f = f;
  unsigned int r = v.u + 0x7fffu + ((v.u >> 16) & 1u);  // RNE (finite values)
  return (unsigned short)(r >> 16);
}
static __device__ __forceinline__ float bf2f(unsigned short b) {
  union { unsigned int u; float f; } v; v.u = ((unsigned int)b) << 16;
  return v.f;
}
static __device__ __forceinline__ short8 cvt8(float4 a, float4 b) {
  short8 r;
  r[0] = (short)f2bf(a.x); r[1] = (short)f2bf(a.y);
  r[2] = (short)f2bf(a.z); r[3] = (short)f2bf(a.w);
  r[4] = (short)f2bf(b.x); r[5] = (short)f2bf(b.y);
  r[6] = (short)f2bf(b.z); r[7] = (short)f2bf(b.w);
  return r;
}

__global__ __launch_bounds__(256) void count_kernel(
    const int4* __restrict__ dst4, int* __restrict__ cnt, int e4) {
  int i = blockIdx.x * 256 + threadIdx.x;
  if (i < e4) {
    int4 d = dst4[i];
    atomicAdd(&cnt[d.x], 1);
    atomicAdd(&cnt[d.y], 1);
    atomicAdd(&cnt[d.z], 1);
    atomicAdd(&cnt[d.w], 1);
  }
}

// per-block sums of cnt
__global__ __launch_bounds__(256) void partial_kernel(
    const int* __restrict__ cnt, int* __restrict__ bsum, int n) {
  __shared__ int wsum[4];
  int i = blockIdx.x * 256 + threadIdx.x;
  int lane = threadIdx.x & 63, wid = threadIdx.x >> 6;
  int v = (i < n) ? cnt[i] : 0;
  #pragma unroll
  for (int off = 1; off < 64; off <<= 1) v += __shfl_xor(v, off, 64);
  if (lane == 0) wsum[wid] = v;
  __syncthreads();
  if (threadIdx.x == 0)
    bsum[blockIdx.x] = wsum[0] + wsum[1] + wsum[2] + wsum[3];
}

// single-block exclusive scan of block partials (nb <= 512)
__global__ __launch_bounds__(512) void scan_partials_kernel(
    const int* __restrict__ bsum, int* __restrict__ bof,
    int* __restrict__ row_ptr, int nb, int n) {
  __shared__ int wsum[8];
  int t = threadIdx.x, lane = t & 63, wid = t >> 6;
  int v = (t < nb) ? bsum[t] : 0;
  int s = v;
  #pragma unroll
  for (int off = 1; off < 64; off <<= 1) {
    int u = __shfl_up(s, off, 64);
    if (lane >= off) s += u;
  }
  if (lane == 63) wsum[wid] = s;
  __syncthreads();
  int add = 0;
  for (int w = 0; w < wid; ++w) add += wsum[w];
  if (t < nb) bof[t] = add + s - v;
  if (t == 511) row_ptr[n] = add + s;  // grand total == E
}

// exclusive rowptr within each block + fused cursor/dinv init
__global__ __launch_bounds__(256) void rowptr_kernel(
    const int* __restrict__ cnt, const int* __restrict__ bof,
    int* __restrict__ row_ptr, int* __restrict__ cursor,
    float* __restrict__ dinv, int n) {
  __shared__ int wsum[4];
  int i = blockIdx.x * 256 + threadIdx.x;
  int lane = threadIdx.x & 63, wid = threadIdx.x >> 6;
  int v = (i < n) ? cnt[i] : 0;
  int s = v;
  #pragma unroll
  for (int off = 1; off < 64; off <<= 1) {
    int u = __shfl_up(s, off, 64);
    if (lane >= off) s += u;
  }
  if (lane == 63) wsum[wid] = s;
  __syncthreads();
  int add = bof[blockIdx.x];
  for (int w = 0; w < wid; ++w) add += wsum[w];
  if (i < n) {
    int excl = add + s - v;
    row_ptr[i] = excl;
    cursor[i] = excl;
    dinv[i] = rsqrtf(1.0f + (float)v);
  }
}

// one u32 per edge: (src << 15) | round(wgt * 32767)
// wgt = dinv[s]*dinv[d] <= 1/sqrt(2) since deg(d) >= 2 incl self-loop.
__global__ __launch_bounds__(256) void fill_kernel(
    const int* __restrict__ src, const int* __restrict__ dst,
    const float* __restrict__ dinv, int* __restrict__ cursor,
    unsigned int* __restrict__ colw, int e) {
  int i = blockIdx.x * 256 + threadIdx.x;
  if (i < e) {
    int s = src[i], d = dst[i];
    float w = dinv[s] * dinv[d];
    int pos = atomicAdd(&cursor[d], 1);
    unsigned int wq = (unsigned int)(w * 32767.0f + 0.5f);
    colw[pos] = ((unsigned int)s << 15) | wq;  // single 4B scattered store
  }
}

// W fp32 [k][n] -> Wt bf16 [n][k]  (128x128), 3 weights in one launch
__global__ __launch_bounds__(256) void wprep_kernel(
    const float* __restrict__ W0, const float* __restrict__ W1,
    const float* __restrict__ W2, unsigned short* __restrict__ Wt0,
    unsigned short* __restrict__ Wt1, unsigned short* __restrict__ Wt2) {
  int which = blockIdx.x >> 6;         // 64 blocks per weight
  int i = (blockIdx.x & 63) * 256 + threadIdx.x;  // 0..16383
  int nn = i >> 7, k = i & 127;        // coalesced 2B writes per n-row
  const float* W = which == 0 ? W0 : (which == 1 ? W1 : W2);
  unsigned short* Wt = which == 0 ? Wt0 : (which == 1 ? Wt1 : Wt2);
  Wt[nn * 128 + k] = f2bf(W[k * 128 + nn]);
}

// hW_bf16[n,128] = h[n,128] @ W via MFMA 16x16x32 bf16.
// Operands swapped (b,a) so D is transposed: lane stores ushort4 runs.
__global__ __launch_bounds__(256) void gemm_mfma_kernel(
    const float* __restrict__ h, const unsigned short* __restrict__ Wt,
    unsigned short* __restrict__ out, int n) {
  int lane = threadIdx.x & 63;
  int wave = threadIdx.x >> 6;
  int row16 = lane & 15;   // node offset within 16 (as B-operand col)
  int kgrp = lane >> 4;    // 0..3
  int node0 = blockIdx.x * 64 + wave * 16;
  int arow = node0 + row16;
  if (arow >= n) arow = n - 1;  // clamp loads; stores guarded

  // h fragments: lane holds h[arow][ks*32 + kgrp*8 + j], j=0..7
  const float4* hrow = (const float4*)(h + (size_t)arow * NFEAT);
  short8 afrag[4];
  #pragma unroll
  for (int ks = 0; ks < 4; ++ks) {
    float4 p0 = hrow[ks * 8 + kgrp * 2];
    float4 p1 = hrow[ks * 8 + kgrp * 2 + 1];
    afrag[ks] = cvt8(p0, p1);
  }

  f32x4 acc[8];
  #pragma unroll
  for (int ct = 0; ct < 8; ++ct) {
    acc[ct] = (f32x4){0.0f, 0.0f, 0.0f, 0.0f};
    const short8* wrow =
        (const short8*)(Wt + (size_t)(ct * 16 + row16) * NFEAT);
    #pragma unroll
    for (int ks = 0; ks < 4; ++ks) {
      short8 bfrag = wrow[ks * 4 + kgrp];
      acc[ct] = __builtin_amdgcn_mfma_f32_16x16x32_bf16(bfrag, afrag[ks],
                                                        acc[ct], 0, 0, 0);
    }
  }

  int orow = node0 + row16;
  if (orow < n) {
    unsigned short* op = out + (size_t)orow * NFEAT + kgrp * 4;
    #pragma unroll
    for (int ct = 0; ct < 8; ++ct) {
      ushort4 o;
      o.x = f2bf(acc[ct][0]); o.y = f2bf(acc[ct][1]);
      o.z = f2bf(acc[ct][2]); o.w = f2bf(acc[ct][3]);
      *(ushort4*)(op + ct * 16) = o;
    }
  }
}

// One wave per node. Paired gathers: lanes 0-31 handle edge j, lanes 32-63
// edge j+1; each lane loads ushort4 (4 feats). shfl_xor(32) combines halves.
// NOTE: every __shfl below is executed in UNIFORM control flow (all 64 lanes
// active) — bpermute from inactive lanes is undefined (R4 bug).
__global__ __launch_bounds__(256) void aggregate_kernel(
    const unsigned short* __restrict__ hWb, const int* __restrict__ row_ptr,
    const unsigned int* __restrict__ colw, const float* __restrict__ dinv,
    const float* __restrict__ bias, const float* __restrict__ resid,
    float* __restrict__ out, int n) {
  int node = blockIdx.x * 4 + (threadIdx.x >> 6);
  int lane = threadIdx.x & 63;
  if (node >= n) return;  // wave-uniform (N % 4 == 0 in practice)
  int half = lane >> 5;   // 0: even edges, 1: odd edges
  int l31 = lane & 31;
  int beg = row_ptr[node], end = row_ptr[node + 1];
  const ushort4* rows = (const ushort4*)hWb;  // 32 x 8B = 256B per row
  float ax = 0.0f, ay = 0.0f, az = 0.0f, aw = 0.0f;
  const float WQI = 1.0f / 32767.0f;

  for (int cbeg = beg; cbeg < end; cbeg += 64) {
    int cnt = end - cbeg; if (cnt > 64) cnt = 64;
    unsigned int pk = 0;                       // lanes >= cnt: (cv,wv)=(0,0)
    if (lane < cnt) pk = colw[cbeg + lane];
    int cv = (int)(pk >> 15);
    float wv = (float)(pk & 0x7fffu) * WQI;
    int j = 0;
    for (; j + 8 <= cnt; j += 8) {
      int s0 = __shfl(cv, j + 0 + half, 64);
      int s1 = __shfl(cv, j + 2 + half, 64);
      int s2 = __shfl(cv, j + 4 + half, 64);
      int s3 = __shfl(cv, j + 6 + half, 64);
      float w0 = __shfl(wv, j + 0 + half, 64);
      float w1 = __shfl(wv, j + 2 + half, 64);
      float w2 = __shfl(wv, j + 4 + half, 64);
      float w3 = __shfl(wv, j + 6 + half, 64);
      ushort4 p0 = rows[(size_t)s0 * 32 + l31];
      ushort4 p1 = rows[(size_t)s1 * 32 + l31];
      ushort4 p2 = rows[(size_t)s2 * 32 + l31];
      ushort4 p3 = rows[(size_t)s3 * 32 + l31];
      ax += w0 * bf2f(p0.x); ay += w0 * bf2f(p0.y);
      az += w0 * bf2f(p0.z); aw += w0 * bf2f(p0.w);
      ax += w1 * bf2f(p1.x); ay += w1 * bf2f(p1.y);
      az += w1 * bf2f(p1.z); aw += w1 * bf2f(p1.w);
      ax += w2 * bf2f(p2.x); ay += w2 * bf2f(p2.y);
      az += w2 * bf2f(p2.z); aw += w2 * bf2f(p2.w);
      ax += w3 * bf2f(p3.x); ay += w3 * bf2f(p3.y);
      az += w3 * bf2f(p3.z); aw += w3 * bf2f(p3.w);
    }
    // branch-free remainder: jj <= 63 always (cnt==64 never reaches here);
    // lanes jj >= cnt hold wv=0 so the term vanishes.
    for (; j < cnt; j += 2) {
      int jj = j + half;
      int s = __shfl(cv, jj, 64);
      float w = __shfl(wv, jj, 64);
      ushort4 p = rows[(size_t)s * 32 + l31];
      ax += w * bf2f(p.x); ay += w * bf2f(p.y);
      az += w * bf2f(p.z); aw += w * bf2f(p.w);
    }
  }

  // combine even/odd halves
  ax += __shfl_xor(ax, 32, 64);
  ay += __shfl_xor(ay, 32, 64);
  az += __shfl_xor(az, 32, 64);
  aw += __shfl_xor(aw, 32, 64);

  if (half == 0) {
    float di = dinv[node];
    float dii = di * di;
    ushort4 ps = rows[(size_t)node * 32 + l31];
    float4 bv = ((const float4*)bias)[l31];
    ax += dii * bf2f(ps.x) + bv.x;
    ay += dii * bf2f(ps.y) + bv.y;
    az += dii * bf2f(ps.z) + bv.z;
    aw += dii * bf2f(ps.w) + bv.w;
    if (resid != nullptr) {
      float4 r = ((const float4*)resid)[(size_t)node * 32 + l31];
      ax += r.x; ay += r.y; az += r.z; aw += r.w;
    }
    float4 o;
    o.x = ax > 0.0f ? ax : expm1f(ax);
    o.y = ay > 0.0f ? ay : expm1f(ay);
    o.z = az > 0.0f ? az : expm1f(az);
    o.w = aw > 0.0f ? aw : expm1f(aw);
    ((float4*)out)[(size_t)node * 32 + l31] = o;
  }
}

extern "C" void kernel_launch(void* const* d_in, const int* in_sizes, int n_in,
                              void* d_out, int out_size, void* d_ws, size_t ws_size,
                              hipStream_t stream) {
  const float* x  = (const float*)d_in[0];
  const int* eidx = (const int*)d_in[1];
  const float* W0 = (const float*)d_in[2];
  const float* b0 = (const float*)d_in[3];
  const float* W1 = (const float*)d_in[4];
  const float* b1 = (const float*)d_in[5];
  const float* W2 = (const float*)d_in[6];
  const float* b2 = (const float*)d_in[7];
  float* outp = (float*)d_out;

  const int N = in_sizes[0] / NFEAT;   // 100000
  const int E = in_sizes[1] / 2;       // 1600000
  const int* src = eidx;
  const int* dst = eidx + E;
  const int NB = (N + 255) / 256;      // 391

  // workspace layout
  const size_t S1 = 401408;                   // > (N+1)*4
  const size_t SB = 4096;                     // > NB*4
  const size_t SW = 32768;                    // 128*128*2
  const size_t SE = (size_t)E * 4;            // 6.4 MB packed edges
  const size_t SH = (size_t)N * NFEAT * 2;    // 25.6 MB bf16 features
  const size_t SF = (size_t)N * NFEAT * 4;    // 51.2 MB fp32 features
  char* p = (char*)d_ws;
  float* dinv   = (float*)p;            p += S1;
  int*   cnt    = (int*)p;              p += S1;
  int*   rowp   = (int*)p;              p += S1;
  int*   cursor = (int*)p;              p += S1;
  int*   bsum   = (int*)p;              p += SB;
  int*   bof    = (int*)p;              p += SB;
  unsigned short* Wt0 = (unsigned short*)p;  p += SW;
  unsigned short* Wt1 = (unsigned short*)p;  p += SW;
  unsigned short* Wt2 = (unsigned short*)p;  p += SW;
  unsigned int* colw = (unsigned int*)p; p += SE;
  unsigned short* hWb = (unsigned short*)p;  p += SH;
  float* hA     = (float*)p;            p += SF;
  float* hB     = (float*)p;            p += SF;

  int ge = (E + 255) / 256;

  // ---- weight prep (independent of CSR) ----
  wprep_kernel<<<192, 256, 0, stream>>>(W0, W1, W2, Wt0, Wt1, Wt2);

  // ---- CSR build ----
  hipMemsetAsync(cnt, 0, (size_t)N * 4, stream);
  count_kernel<<<(E / 4 + 255) / 256, 256, 0, stream>>>((const int4*)dst, cnt,
                                                        E / 4);
  partial_kernel<<<NB, 256, 0, stream>>>(cnt, bsum, N);
  scan_partials_kernel<<<1, 512, 0, stream>>>(bsum, bof, rowp, NB, N);
  rowptr_kernel<<<NB, 256, 0, stream>>>(cnt, bof, rowp, cursor, dinv, N);
  fill_kernel<<<ge, 256, 0, stream>>>(src, dst, dinv, cursor, colw, E);

  int gemm_blocks = (N + 63) / 64;    // 1563
  int agg_blocks = (N + 3) / 4;       // one wave per node

  // ---- layer 0: no residual ----
  gemm_mfma_kernel<<<gemm_blocks, 256, 0, stream>>>(x, Wt0, hWb, N);
  aggregate_kernel<<<agg_blocks, 256, 0, stream>>>(hWb, rowp, colw, dinv,
                                                   b0, nullptr, hA, N);
  // ---- layer 1: residual ----
  gemm_mfma_kernel<<<gemm_blocks, 256, 0, stream>>>(hA, Wt1, hWb, N);
  aggregate_kernel<<<agg_blocks, 256, 0, stream>>>(hWb, rowp, colw, dinv,
                                                   b1, hA, hB, N);
  // ---- layer 2: residual, write d_out ----
  gemm_mfma_kernel<<<gemm_blocks, 256, 0, stream>>>(hB, Wt2, hWb, N);
  aggregate_kernel<<<agg_blocks, 256, 0, stream>>>(hWb, rowp, colw, dinv,
                                                   b2, hB, outp, N);
}

// Round 6
// 577.828 us; speedup vs baseline: 1.8482x; 1.0095x over previous
//
#include <hip/hip_runtime.h>
#include <math.h>

// GCN: h = elu(D^-1/2 (A+I) D^-1/2 (h W) + b [+ resid])
// N=100000 nodes, E=1600000 edges, 128 features per layer.
//
// R6 changes vs R5:
//  - GEMM: LDS-staged tile (coalesced float4 global loads -> bf16 LDS,
//    pitch 136 shorts to break bank aliasing, ds_read_b128 fragments).
//    R5 loaded 16B fragments straight from global, scattered across 16
//    rows per wave -> ~75us/gemm vs ~13us memory floor.
//  - gemm0 fused with count_kernel (block-range split, independent work).
//  - fill: nontemporal scattered store (WRITE_SIZE is line churn:
//    1.6M stores x 64B = ~102MB regardless of record size).

#define NFEAT 128
#define LDSP 136  // LDS row pitch in shorts (128 + 8 pad)

typedef short short8 __attribute__((ext_vector_type(8)));
typedef float f32x4 __attribute__((ext_vector_type(4)));

static __device__ __forceinline__ unsigned short f2bf(float f) {
  union { float f; unsigned int u; } v; v.f = f;
  unsigned int r = v.u + 0x7fffu + ((v.u >> 16) & 1u);  // RNE (finite values)
  return (unsigned short)(r >> 16);
}
static __device__ __forceinline__ float bf2f(unsigned short b) {
  union { unsigned int u; float f; } v; v.u = ((unsigned int)b) << 16;
  return v.f;
}

// ---------------- CSR build ----------------

// per-block sums of cnt
__global__ __launch_bounds__(256) void partial_kernel(
    const int* __restrict__ cnt, int* __restrict__ bsum, int n) {
  __shared__ int wsum[4];
  int i = blockIdx.x * 256 + threadIdx.x;
  int lane = threadIdx.x & 63, wid = threadIdx.x >> 6;
  int v = (i < n) ? cnt[i] : 0;
  #pragma unroll
  for (int off = 1; off < 64; off <<= 1) v += __shfl_xor(v, off, 64);
  if (lane == 0) wsum[wid] = v;
  __syncthreads();
  if (threadIdx.x == 0)
    bsum[blockIdx.x] = wsum[0] + wsum[1] + wsum[2] + wsum[3];
}

// single-block exclusive scan of block partials (nb <= 512)
__global__ __launch_bounds__(512) void scan_partials_kernel(
    const int* __restrict__ bsum, int* __restrict__ bof,
    int* __restrict__ row_ptr, int nb, int n) {
  __shared__ int wsum[8];
  int t = threadIdx.x, lane = t & 63, wid = t >> 6;
  int v = (t < nb) ? bsum[t] : 0;
  int s = v;
  #pragma unroll
  for (int off = 1; off < 64; off <<= 1) {
    int u = __shfl_up(s, off, 64);
    if (lane >= off) s += u;
  }
  if (lane == 63) wsum[wid] = s;
  __syncthreads();
  int add = 0;
  for (int w = 0; w < wid; ++w) add += wsum[w];
  if (t < nb) bof[t] = add + s - v;
  if (t == 511) row_ptr[n] = add + s;  // grand total == E
}

// exclusive rowptr within each block + fused cursor/dinv init
__global__ __launch_bounds__(256) void rowptr_kernel(
    const int* __restrict__ cnt, const int* __restrict__ bof,
    int* __restrict__ row_ptr, int* __restrict__ cursor,
    float* __restrict__ dinv, int n) {
  __shared__ int wsum[4];
  int i = blockIdx.x * 256 + threadIdx.x;
  int lane = threadIdx.x & 63, wid = threadIdx.x >> 6;
  int v = (i < n) ? cnt[i] : 0;
  int s = v;
  #pragma unroll
  for (int off = 1; off < 64; off <<= 1) {
    int u = __shfl_up(s, off, 64);
    if (lane >= off) s += u;
  }
  if (lane == 63) wsum[wid] = s;
  __syncthreads();
  int add = bof[blockIdx.x];
  for (int w = 0; w < wid; ++w) add += wsum[w];
  if (i < n) {
    int excl = add + s - v;
    row_ptr[i] = excl;
    cursor[i] = excl;
    dinv[i] = rsqrtf(1.0f + (float)v);
  }
}

// one u32 per edge: (src << 15) | round(wgt * 32767)
// wgt = dinv[s]*dinv[d] <= 1/sqrt(2) since deg >= 2 incl self-loop.
__global__ __launch_bounds__(256) void fill_kernel(
    const int* __restrict__ src, const int* __restrict__ dst,
    const float* __restrict__ dinv, int* __restrict__ cursor,
    unsigned int* __restrict__ colw, int e) {
  int i = blockIdx.x * 256 + threadIdx.x;
  if (i < e) {
    int s = src[i], d = dst[i];
    float w = dinv[s] * dinv[d];
    int pos = atomicAdd(&cursor[d], 1);
    unsigned int wq = (unsigned int)(w * 32767.0f + 0.5f);
    __builtin_nontemporal_store(((unsigned int)s << 15) | wq, &colw[pos]);
  }
}

// W fp32 [k][n] -> Wt bf16 [n][k]  (128x128), 3 weights in one launch
__global__ __launch_bounds__(256) void wprep_kernel(
    const float* __restrict__ W0, const float* __restrict__ W1,
    const float* __restrict__ W2, unsigned short* __restrict__ Wt0,
    unsigned short* __restrict__ Wt1, unsigned short* __restrict__ Wt2) {
  int which = blockIdx.x >> 6;         // 64 blocks per weight
  int i = (blockIdx.x & 63) * 256 + threadIdx.x;  // 0..16383
  int nn = i >> 7, k = i & 127;
  const float* W = which == 0 ? W0 : (which == 1 ? W1 : W2);
  unsigned short* Wt = which == 0 ? Wt0 : (which == 1 ? Wt1 : Wt2);
  Wt[nn * 128 + k] = f2bf(W[k * 128 + nn]);
}

// ---------------- GEMM (LDS-staged MFMA) ----------------
// hW_bf16[n,128] = h[n,128] @ W. 64 nodes/block. Operand-swapped MFMA so
// lane stores contiguous ushort4 runs of its own node row.
static __device__ __forceinline__ void gemm_body(
    int gblk, const float* __restrict__ h, const unsigned short* __restrict__ Wt,
    unsigned short* __restrict__ out, int n, unsigned short* lds) {
  int t = threadIdx.x;
  int block0 = gblk * 64;

  // stage: 64 rows x 128 feats fp32 -> bf16 LDS, fully coalesced
  const float4* h4 = (const float4*)h;
  #pragma unroll
  for (int i = 0; i < 8; ++i) {
    int idx = t + 256 * i;          // 0..2047
    int r = idx >> 5, c = idx & 31; // row, float4-col
    int grow = block0 + r; if (grow >= n) grow = n - 1;
    float4 v = h4[(size_t)grow * 32 + c];
    ushort4 b;
    b.x = f2bf(v.x); b.y = f2bf(v.y); b.z = f2bf(v.z); b.w = f2bf(v.w);
    *(ushort4*)&lds[r * LDSP + c * 4] = b;
  }
  __syncthreads();

  int lane = t & 63, wave = t >> 6;
  int row16 = lane & 15;  // node within wave's 16
  int kgrp = lane >> 4;   // 0..3

  // A fragments from LDS: h[row][ks*32 + kgrp*8 + j], j=0..7 (16B aligned)
  short8 afrag[4];
  #pragma unroll
  for (int ks = 0; ks < 4; ++ks)
    afrag[ks] =
        *(const short8*)&lds[(wave * 16 + row16) * LDSP + ks * 32 + kgrp * 8];

  f32x4 acc[8];
  #pragma unroll
  for (int ct = 0; ct < 8; ++ct) {
    acc[ct] = (f32x4){0.0f, 0.0f, 0.0f, 0.0f};
    const short8* wrow =
        (const short8*)(Wt + (size_t)(ct * 16 + row16) * NFEAT);
    #pragma unroll
    for (int ks = 0; ks < 4; ++ks) {
      acc[ct] = __builtin_amdgcn_mfma_f32_16x16x32_bf16(
          wrow[ks * 4 + kgrp], afrag[ks], acc[ct], 0, 0, 0);
    }
  }

  int orow = block0 + wave * 16 + row16;
  if (orow < n) {
    unsigned short* op = out + (size_t)orow * NFEAT + kgrp * 4;
    #pragma unroll
    for (int ct = 0; ct < 8; ++ct) {
      ushort4 o;
      o.x = f2bf(acc[ct][0]); o.y = f2bf(acc[ct][1]);
      o.z = f2bf(acc[ct][2]); o.w = f2bf(acc[ct][3]);
      *(ushort4*)(op + ct * 16) = o;
    }
  }
}

__global__ __launch_bounds__(256) void gemm_mfma_kernel(
    const float* __restrict__ h, const unsigned short* __restrict__ Wt,
    unsigned short* __restrict__ out, int n) {
  __shared__ unsigned short lds[64 * LDSP];
  gemm_body(blockIdx.x, h, Wt, out, n, lds);
}

// gemm0 and degree-count are independent -> one dispatch, block-range split
__global__ __launch_bounds__(256) void fused_g0_count_kernel(
    const float* __restrict__ x, const unsigned short* __restrict__ Wt0,
    unsigned short* __restrict__ hWb, int n, int gb,
    const int4* __restrict__ dst4, int* __restrict__ cnt, int e4) {
  __shared__ unsigned short lds[64 * LDSP];
  if ((int)blockIdx.x < gb) {
    gemm_body(blockIdx.x, x, Wt0, hWb, n, lds);
  } else {
    int i = ((int)blockIdx.x - gb) * 256 + threadIdx.x;
    if (i < e4) {
      int4 d = dst4[i];
      atomicAdd(&cnt[d.x], 1);
      atomicAdd(&cnt[d.y], 1);
      atomicAdd(&cnt[d.z], 1);
      atomicAdd(&cnt[d.w], 1);
    }
  }
}

// ---------------- Aggregate ----------------
// One wave per node. Paired gathers: lanes 0-31 handle edge j, lanes 32-63
// edge j+1; each lane loads ushort4 (4 feats). shfl_xor(32) combines halves.
// All __shfl in uniform control flow (bpermute from inactive lanes is UB).
__global__ __launch_bounds__(256) void aggregate_kernel(
    const unsigned short* __restrict__ hWb, const int* __restrict__ row_ptr,
    const unsigned int* __restrict__ colw, const float* __restrict__ dinv,
    const float* __restrict__ bias, const float* __restrict__ resid,
    float* __restrict__ out, int n) {
  int node = blockIdx.x * 4 + (threadIdx.x >> 6);
  int lane = threadIdx.x & 63;
  if (node >= n) return;  // wave-uniform
  int half = lane >> 5;
  int l31 = lane & 31;
  int beg = row_ptr[node], end = row_ptr[node + 1];
  const ushort4* rows = (const ushort4*)hWb;  // 32 x 8B = 256B per row
  float ax = 0.0f, ay = 0.0f, az = 0.0f, aw = 0.0f;
  const float WQI = 1.0f / 32767.0f;

  for (int cbeg = beg; cbeg < end; cbeg += 64) {
    int cnt = end - cbeg; if (cnt > 64) cnt = 64;
    unsigned int pk = 0;                 // lanes >= cnt: (cv,wv)=(0,0)
    if (lane < cnt) pk = colw[cbeg + lane];
    int cv = (int)(pk >> 15);
    float wv = (float)(pk & 0x7fffu) * WQI;
    int j = 0;
    for (; j + 8 <= cnt; j += 8) {
      int s0 = __shfl(cv, j + 0 + half, 64);
      int s1 = __shfl(cv, j + 2 + half, 64);
      int s2 = __shfl(cv, j + 4 + half, 64);
      int s3 = __shfl(cv, j + 6 + half, 64);
      float w0 = __shfl(wv, j + 0 + half, 64);
      float w1 = __shfl(wv, j + 2 + half, 64);
      float w2 = __shfl(wv, j + 4 + half, 64);
      float w3 = __shfl(wv, j + 6 + half, 64);
      ushort4 p0 = rows[(size_t)s0 * 32 + l31];
      ushort4 p1 = rows[(size_t)s1 * 32 + l31];
      ushort4 p2 = rows[(size_t)s2 * 32 + l31];
      ushort4 p3 = rows[(size_t)s3 * 32 + l31];
      ax += w0 * bf2f(p0.x); ay += w0 * bf2f(p0.y);
      az += w0 * bf2f(p0.z); aw += w0 * bf2f(p0.w);
      ax += w1 * bf2f(p1.x); ay += w1 * bf2f(p1.y);
      az += w1 * bf2f(p1.z); aw += w1 * bf2f(p1.w);
      ax += w2 * bf2f(p2.x); ay += w2 * bf2f(p2.y);
      az += w2 * bf2f(p2.z); aw += w2 * bf2f(p2.w);
      ax += w3 * bf2f(p3.x); ay += w3 * bf2f(p3.y);
      az += w3 * bf2f(p3.z); aw += w3 * bf2f(p3.w);
    }
    // branch-free remainder: jj <= 63 always; lanes >= cnt hold wv=0.
    for (; j < cnt; j += 2) {
      int jj = j + half;
      int s = __shfl(cv, jj, 64);
      float w = __shfl(wv, jj, 64);
      ushort4 p = rows[(size_t)s * 32 + l31];
      ax += w * bf2f(p.x); ay += w * bf2f(p.y);
      az += w * bf2f(p.z); aw += w * bf2f(p.w);
    }
  }

  ax += __shfl_xor(ax, 32, 64);
  ay += __shfl_xor(ay, 32, 64);
  az += __shfl_xor(az, 32, 64);
  aw += __shfl_xor(aw, 32, 64);

  if (half == 0) {
    float di = dinv[node];
    float dii = di * di;
    ushort4 ps = rows[(size_t)node * 32 + l31];
    float4 bv = ((const float4*)bias)[l31];
    ax += dii * bf2f(ps.x) + bv.x;
    ay += dii * bf2f(ps.y) + bv.y;
    az += dii * bf2f(ps.z) + bv.z;
    aw += dii * bf2f(ps.w) + bv.w;
    if (resid != nullptr) {
      float4 r = ((const float4*)resid)[(size_t)node * 32 + l31];
      ax += r.x; ay += r.y; az += r.z; aw += r.w;
    }
    float4 o;
    o.x = ax > 0.0f ? ax : expm1f(ax);
    o.y = ay > 0.0f ? ay : expm1f(ay);
    o.z = az > 0.0f ? az : expm1f(az);
    o.w = aw > 0.0f ? aw : expm1f(aw);
    ((float4*)out)[(size_t)node * 32 + l31] = o;
  }
}

extern "C" void kernel_launch(void* const* d_in, const int* in_sizes, int n_in,
                              void* d_out, int out_size, void* d_ws, size_t ws_size,
                              hipStream_t stream) {
  const float* x  = (const float*)d_in[0];
  const int* eidx = (const int*)d_in[1];
  const float* W0 = (const float*)d_in[2];
  const float* b0 = (const float*)d_in[3];
  const float* W1 = (const float*)d_in[4];
  const float* b1 = (const float*)d_in[5];
  const float* W2 = (const float*)d_in[6];
  const float* b2 = (const float*)d_in[7];
  float* outp = (float*)d_out;

  const int N = in_sizes[0] / NFEAT;   // 100000
  const int E = in_sizes[1] / 2;       // 1600000
  const int* src = eidx;
  const int* dst = eidx + E;
  const int NB = (N + 255) / 256;      // 391

  // workspace layout
  const size_t S1 = 401408;                   // > (N+1)*4
  const size_t SB = 4096;                     // > NB*4
  const size_t SW = 32768;                    // 128*128*2
  const size_t SE = (size_t)E * 4;            // 6.4 MB packed edges
  const size_t SH = (size_t)N * NFEAT * 2;    // 25.6 MB bf16 features
  const size_t SF = (size_t)N * NFEAT * 4;    // 51.2 MB fp32 features
  char* p = (char*)d_ws;
  float* dinv   = (float*)p;            p += S1;
  int*   cnt    = (int*)p;              p += S1;
  int*   rowp   = (int*)p;              p += S1;
  int*   cursor = (int*)p;              p += S1;
  int*   bsum   = (int*)p;              p += SB;
  int*   bof    = (int*)p;              p += SB;
  unsigned short* Wt0 = (unsigned short*)p;  p += SW;
  unsigned short* Wt1 = (unsigned short*)p;  p += SW;
  unsigned short* Wt2 = (unsigned short*)p;  p += SW;
  unsigned int* colw = (unsigned int*)p; p += SE;
  unsigned short* hWb = (unsigned short*)p;  p += SH;
  float* hA     = (float*)p;            p += SF;
  float* hB     = (float*)p;            p += SF;

  int ge = (E + 255) / 256;
  int gemm_blocks = (N + 63) / 64;    // 1563
  int count_blocks = (E / 4 + 255) / 256;  // 1563
  int agg_blocks = (N + 3) / 4;       // one wave per node

  // ---- weight prep, then fused {gemm0 + degree count} ----
  wprep_kernel<<<192, 256, 0, stream>>>(W0, W1, W2, Wt0, Wt1, Wt2);
  hipMemsetAsync(cnt, 0, (size_t)N * 4, stream);
  fused_g0_count_kernel<<<gemm_blocks + count_blocks, 256, 0, stream>>>(
      x, Wt0, hWb, N, gemm_blocks, (const int4*)dst, cnt, E / 4);

  // ---- CSR build ----
  partial_kernel<<<NB, 256, 0, stream>>>(cnt, bsum, N);
  scan_partials_kernel<<<1, 512, 0, stream>>>(bsum, bof, rowp, NB, N);
  rowptr_kernel<<<NB, 256, 0, stream>>>(cnt, bof, rowp, cursor, dinv, N);
  fill_kernel<<<ge, 256, 0, stream>>>(src, dst, dinv, cursor, colw, E);

  // ---- layer 0 aggregate (gemm0 already done) ----
  aggregate_kernel<<<agg_blocks, 256, 0, stream>>>(hWb, rowp, colw, dinv,
                                                   b0, nullptr, hA, N);
  // ---- layer 1 ----
  gemm_mfma_kernel<<<gemm_blocks, 256, 0, stream>>>(hA, Wt1, hWb, N);
  aggregate_kernel<<<agg_blocks, 256, 0, stream>>>(hWb, rowp, colw, dinv,
                                                   b1, hA, hB, N);
  // ---- layer 2, write d_out ----
  gemm_mfma_kernel<<<gemm_blocks, 256, 0, stream>>>(hB, Wt2, hWb, N);
  aggregate_kernel<<<agg_blocks, 256, 0, stream>>>(hWb, rowp, colw, dinv,
                                                   b2, hB, outp, N);
}

// Round 7
// 487.817 us; speedup vs baseline: 2.1892x; 1.1845x over previous
//
#include <hip/hip_runtime.h>
#include <math.h>

// GCN: h = elu(D^-1/2 (A+I) D^-1/2 (h W) + b [+ resid])
// N=100000 nodes, E=1600000 edges, 128 features per layer.
//
// R7 changes vs R6: CSR build rebuilt as two-level bucketed counting sort.
//  - R6 evidence: count_kernel's global atomics cost ~49MB HBM write churn;
//    fill_kernel's random 4B scatter cost ~102MB (per-store line churn,
//    cross-XCD lines never merge). Both replaced:
//  - Pass A (fused w/ gemm0): LDS hist of edges per 512-node bucket.
//  - Pass B: scan 196 bucket counts (1 block).
//  - Pass C: scatter (dst,src) u64 -> bucket-major ebuf via block-chunk
//    reservation (contiguous ~170B chunks per bucket -> lines fill).
//  - Pass D1 (block/bucket): LDS degree hist + local scan -> rowp, dinv.
//    NO global-atomic degree count at all.
//  - Pass D2 (block/bucket): LDS cursors, write colw into the bucket's own
//    ~32KB region -> writes confined to one block/XCD -> lines merge.

#define NFEAT 128
#define LDSP 136   // LDS row pitch in shorts (128 + 8 pad)
#define BSH 9      // bucket shift: 512 nodes/bucket
#define BWID 512

typedef short short8 __attribute__((ext_vector_type(8)));
typedef float f32x4 __attribute__((ext_vector_type(4)));

static __device__ __forceinline__ unsigned short f2bf(float f) {
  union { float f; unsigned int u; } v; v.f = f;
  unsigned int r = v.u + 0x7fffu + ((v.u >> 16) & 1u);  // RNE (finite values)
  return (unsigned short)(r >> 16);
}
static __device__ __forceinline__ float bf2f(unsigned short b) {
  union { unsigned int u; float f; } v; v.u = ((unsigned int)b) << 16;
  return v.f;
}

// ---------------- GEMM body (LDS-staged MFMA) ----------------
// hW_bf16[n,128] = h[n,128] @ W. 64 nodes/block, operand-swapped MFMA so
// each lane stores contiguous ushort4 runs of its own node row.
static __device__ __forceinline__ void gemm_body(
    int gblk, const float* __restrict__ h, const unsigned short* __restrict__ Wt,
    unsigned short* __restrict__ out, int n, unsigned short* lds) {
  int t = threadIdx.x;
  int block0 = gblk * 64;

  const float4* h4 = (const float4*)h;
  #pragma unroll
  for (int i = 0; i < 8; ++i) {
    int idx = t + 256 * i;          // 0..2047
    int r = idx >> 5, c = idx & 31; // row, float4-col
    int grow = block0 + r; if (grow >= n) grow = n - 1;
    float4 v = h4[(size_t)grow * 32 + c];
    ushort4 b;
    b.x = f2bf(v.x); b.y = f2bf(v.y); b.z = f2bf(v.z); b.w = f2bf(v.w);
    *(ushort4*)&lds[r * LDSP + c * 4] = b;
  }
  __syncthreads();

  int lane = t & 63, wave = t >> 6;
  int row16 = lane & 15;
  int kgrp = lane >> 4;

  short8 afrag[4];
  #pragma unroll
  for (int ks = 0; ks < 4; ++ks)
    afrag[ks] =
        *(const short8*)&lds[(wave * 16 + row16) * LDSP + ks * 32 + kgrp * 8];

  f32x4 acc[8];
  #pragma unroll
  for (int ct = 0; ct < 8; ++ct) {
    acc[ct] = (f32x4){0.0f, 0.0f, 0.0f, 0.0f};
    const short8* wrow =
        (const short8*)(Wt + (size_t)(ct * 16 + row16) * NFEAT);
    #pragma unroll
    for (int ks = 0; ks < 4; ++ks) {
      acc[ct] = __builtin_amdgcn_mfma_f32_16x16x32_bf16(
          wrow[ks * 4 + kgrp], afrag[ks], acc[ct], 0, 0, 0);
    }
  }

  int orow = block0 + wave * 16 + row16;
  if (orow < n) {
    unsigned short* op = out + (size_t)orow * NFEAT + kgrp * 4;
    #pragma unroll
    for (int ct = 0; ct < 8; ++ct) {
      ushort4 o;
      o.x = f2bf(acc[ct][0]); o.y = f2bf(acc[ct][1]);
      o.z = f2bf(acc[ct][2]); o.w = f2bf(acc[ct][3]);
      *(ushort4*)(op + ct * 16) = o;
    }
  }
}

__global__ __launch_bounds__(256) void gemm_mfma_kernel(
    const float* __restrict__ h, const unsigned short* __restrict__ Wt,
    unsigned short* __restrict__ out, int n) {
  __shared__ int lds_i[64 * LDSP / 2];
  gemm_body(blockIdx.x, h, Wt, out, n, (unsigned short*)lds_i);
}

// gemm0 fused with Pass A (bucket histogram) — independent work.
__global__ __launch_bounds__(256) void fused_g0_hist_kernel(
    const float* __restrict__ x, const unsigned short* __restrict__ Wt0,
    unsigned short* __restrict__ hWb, int n, int gb,
    const int4* __restrict__ dst4, int* __restrict__ bcnt, int e4, int nbuc) {
  __shared__ int lds_i[64 * LDSP / 2];
  int t = threadIdx.x;
  if ((int)blockIdx.x < gb) {
    gemm_body(blockIdx.x, x, Wt0, hWb, n, (unsigned short*)lds_i);
  } else {
    int* hist = lds_i;
    hist[t] = 0;
    __syncthreads();
    int base = ((int)blockIdx.x - gb) * 1024;
    #pragma unroll
    for (int i = 0; i < 4; ++i) {
      int idx = base + t + 256 * i;
      if (idx < e4) {
        int4 d = dst4[idx];
        atomicAdd(&hist[d.x >> BSH], 1);
        atomicAdd(&hist[d.y >> BSH], 1);
        atomicAdd(&hist[d.z >> BSH], 1);
        atomicAdd(&hist[d.w >> BSH], 1);
      }
    }
    __syncthreads();
    int h = hist[t];
    if (t < nbuc && h) atomicAdd(&bcnt[t], h);
  }
}

// Pass B: exclusive scan of bucket counts (nbuc <= 256), init gcur, rowp[n]=E
__global__ __launch_bounds__(256) void scan_buckets_kernel(
    const int* __restrict__ bcnt, int* __restrict__ boff,
    int* __restrict__ gcur, int* __restrict__ rowp, int nbuc, int n, int e) {
  __shared__ int wsum[4];
  int t = threadIdx.x, lane = t & 63, wid = t >> 6;
  int v = (t < nbuc) ? bcnt[t] : 0;
  int s = v;
  #pragma unroll
  for (int off = 1; off < 64; off <<= 1) {
    int u = __shfl_up(s, off, 64);
    if (lane >= off) s += u;
  }
  if (lane == 63) wsum[wid] = s;
  __syncthreads();
  int add = 0;
  for (int w = 0; w < wid; ++w) add += wsum[w];
  int incl = add + s;
  if (t < nbuc) { boff[t] = incl - v; gcur[t] = incl - v; }
  if (t == nbuc - 1) boff[nbuc] = incl;  // == E
  if (t == 0) rowp[n] = e;
}

// Pass C: scatter (dst,src) u64 into bucket-major ebuf, block-chunked.
__global__ __launch_bounds__(256) void bucket_scatter_kernel(
    const int4* __restrict__ src4, const int4* __restrict__ dst4,
    int* __restrict__ gcur, unsigned long long* __restrict__ ebuf, int e4) {
  __shared__ int hist[256];
  __shared__ int cbase[256];
  __shared__ int cur[256];
  int t = threadIdx.x;
  hist[t] = 0; cur[t] = 0;
  __syncthreads();
  int base = blockIdx.x * 1024;
  int4 dv[4], sv[4];
  bool val[4];
  #pragma unroll
  for (int i = 0; i < 4; ++i) {
    int idx = base + t + 256 * i;
    val[i] = idx < e4;
    if (val[i]) {
      dv[i] = dst4[idx];
      sv[i] = src4[idx];
      atomicAdd(&hist[dv[i].x >> BSH], 1);
      atomicAdd(&hist[dv[i].y >> BSH], 1);
      atomicAdd(&hist[dv[i].z >> BSH], 1);
      atomicAdd(&hist[dv[i].w >> BSH], 1);
    }
  }
  __syncthreads();
  int h = hist[t];
  if (h) cbase[t] = atomicAdd(&gcur[t], h);  // hist[t]==0 for t>=nbuc
  __syncthreads();
  #pragma unroll
  for (int i = 0; i < 4; ++i) {
    if (val[i]) {
      int d, s, b, p;
      d = dv[i].x; s = sv[i].x; b = d >> BSH;
      p = cbase[b] + atomicAdd(&cur[b], 1);
      ebuf[p] = ((unsigned long long)(unsigned)d << 32) | (unsigned)s;
      d = dv[i].y; s = sv[i].y; b = d >> BSH;
      p = cbase[b] + atomicAdd(&cur[b], 1);
      ebuf[p] = ((unsigned long long)(unsigned)d << 32) | (unsigned)s;
      d = dv[i].z; s = sv[i].z; b = d >> BSH;
      p = cbase[b] + atomicAdd(&cur[b], 1);
      ebuf[p] = ((unsigned long long)(unsigned)d << 32) | (unsigned)s;
      d = dv[i].w; s = sv[i].w; b = d >> BSH;
      p = cbase[b] + atomicAdd(&cur[b], 1);
      ebuf[p] = ((unsigned long long)(unsigned)d << 32) | (unsigned)s;
    }
  }
}

// Pass D1: per-bucket degree hist (LDS) + local scan -> rowp, dinv.
__global__ __launch_bounds__(256) void bucket_deg_kernel(
    const unsigned long long* __restrict__ ebuf, const int* __restrict__ boff,
    int* __restrict__ rowp, float* __restrict__ dinv, int n) {
  __shared__ int deg[BWID];
  __shared__ int wsum[4];
  int t = threadIdx.x;
  int b = blockIdx.x, node0 = b << BSH;
  deg[t] = 0; deg[t + 256] = 0;
  __syncthreads();
  int ebeg = boff[b], eend = boff[b + 1];
  for (int i = ebeg + t; i < eend; i += 256) {
    int d = (int)(ebuf[i] >> 32);
    atomicAdd(&deg[d - node0], 1);
  }
  __syncthreads();
  int d0 = deg[2 * t], d1 = deg[2 * t + 1];
  int s = d0 + d1;
  int lane = t & 63, wid = t >> 6;
  int sc = s;
  #pragma unroll
  for (int off = 1; off < 64; off <<= 1) {
    int u = __shfl_up(sc, off, 64);
    if (lane >= off) sc += u;
  }
  if (lane == 63) wsum[wid] = sc;
  __syncthreads();
  int add = 0;
  for (int w = 0; w < wid; ++w) add += wsum[w];
  int excl = ebeg + add + sc - s;  // rowp of node 2t in this bucket
  int node = node0 + 2 * t;
  if (node < n) {
    rowp[node] = excl;
    dinv[node] = rsqrtf(1.0f + (float)d0);
  }
  if (node + 1 < n) {
    rowp[node + 1] = excl + d0;
    dinv[node + 1] = rsqrtf(1.0f + (float)d1);
  }
}

// Pass D2: per-bucket fine scatter into colw (writes confined to the
// bucket's ~32KB region -> one block/XCD -> L2 lines merge fully).
__global__ __launch_bounds__(256) void bucket_fill_kernel(
    const unsigned long long* __restrict__ ebuf, const int* __restrict__ boff,
    const int* __restrict__ rowp, const float* __restrict__ dinv,
    unsigned int* __restrict__ colw, int n) {
  __shared__ int cur[BWID];
  int t = threadIdx.x;
  int b = blockIdx.x, node0 = b << BSH;
  for (int k = t; k < BWID; k += 256) {
    int node = node0 + k;
    cur[k] = (node < n) ? rowp[node] : 0;
  }
  __syncthreads();
  int ebeg = boff[b], eend = boff[b + 1];
  for (int i = ebeg + t; i < eend; i += 256) {
    unsigned long long p = ebuf[i];
    int d = (int)(p >> 32);
    int s = (int)(unsigned int)p;
    float w = dinv[s] * dinv[d];
    unsigned int wq = (unsigned int)(w * 32767.0f + 0.5f);
    int pos = atomicAdd(&cur[d - node0], 1);
    colw[pos] = ((unsigned int)s << 15) | wq;
  }
}

// W fp32 [k][n] -> Wt bf16 [n][k]  (128x128), 3 weights in one launch
__global__ __launch_bounds__(256) void wprep_kernel(
    const float* __restrict__ W0, const float* __restrict__ W1,
    const float* __restrict__ W2, unsigned short* __restrict__ Wt0,
    unsigned short* __restrict__ Wt1, unsigned short* __restrict__ Wt2) {
  int which = blockIdx.x >> 6;
  int i = (blockIdx.x & 63) * 256 + threadIdx.x;
  int nn = i >> 7, k = i & 127;
  const float* W = which == 0 ? W0 : (which == 1 ? W1 : W2);
  unsigned short* Wt = which == 0 ? Wt0 : (which == 1 ? Wt1 : Wt2);
  Wt[nn * 128 + k] = f2bf(W[k * 128 + nn]);
}

// ---------------- Aggregate ----------------
// One wave per node. Paired gathers: lanes 0-31 edge j, lanes 32-63 edge j+1,
// ushort4/lane. All __shfl in uniform control flow (inactive-lane bpermute UB).
__global__ __launch_bounds__(256) void aggregate_kernel(
    const unsigned short* __restrict__ hWb, const int* __restrict__ row_ptr,
    const unsigned int* __restrict__ colw, const float* __restrict__ dinv,
    const float* __restrict__ bias, const float* __restrict__ resid,
    float* __restrict__ out, int n) {
  int node = blockIdx.x * 4 + (threadIdx.x >> 6);
  int lane = threadIdx.x & 63;
  if (node >= n) return;  // wave-uniform
  int half = lane >> 5;
  int l31 = lane & 31;
  int beg = row_ptr[node], end = row_ptr[node + 1];
  const ushort4* rows = (const ushort4*)hWb;
  float ax = 0.0f, ay = 0.0f, az = 0.0f, aw = 0.0f;
  const float WQI = 1.0f / 32767.0f;

  for (int cbeg = beg; cbeg < end; cbeg += 64) {
    int cnt = end - cbeg; if (cnt > 64) cnt = 64;
    unsigned int pk = 0;                 // lanes >= cnt: (cv,wv)=(0,0)
    if (lane < cnt) pk = colw[cbeg + lane];
    int cv = (int)(pk >> 15);
    float wv = (float)(pk & 0x7fffu) * WQI;
    int j = 0;
    for (; j + 8 <= cnt; j += 8) {
      int s0 = __shfl(cv, j + 0 + half, 64);
      int s1 = __shfl(cv, j + 2 + half, 64);
      int s2 = __shfl(cv, j + 4 + half, 64);
      int s3 = __shfl(cv, j + 6 + half, 64);
      float w0 = __shfl(wv, j + 0 + half, 64);
      float w1 = __shfl(wv, j + 2 + half, 64);
      float w2 = __shfl(wv, j + 4 + half, 64);
      float w3 = __shfl(wv, j + 6 + half, 64);
      ushort4 p0 = rows[(size_t)s0 * 32 + l31];
      ushort4 p1 = rows[(size_t)s1 * 32 + l31];
      ushort4 p2 = rows[(size_t)s2 * 32 + l31];
      ushort4 p3 = rows[(size_t)s3 * 32 + l31];
      ax += w0 * bf2f(p0.x); ay += w0 * bf2f(p0.y);
      az += w0 * bf2f(p0.z); aw += w0 * bf2f(p0.w);
      ax += w1 * bf2f(p1.x); ay += w1 * bf2f(p1.y);
      az += w1 * bf2f(p1.z); aw += w1 * bf2f(p1.w);
      ax += w2 * bf2f(p2.x); ay += w2 * bf2f(p2.y);
      az += w2 * bf2f(p2.z); aw += w2 * bf2f(p2.w);
      ax += w3 * bf2f(p3.x); ay += w3 * bf2f(p3.y);
      az += w3 * bf2f(p3.z); aw += w3 * bf2f(p3.w);
    }
    // branch-free remainder: jj <= 63 always; lanes >= cnt hold wv=0.
    for (; j < cnt; j += 2) {
      int jj = j + half;
      int s = __shfl(cv, jj, 64);
      float w = __shfl(wv, jj, 64);
      ushort4 p = rows[(size_t)s * 32 + l31];
      ax += w * bf2f(p.x); ay += w * bf2f(p.y);
      az += w * bf2f(p.z); aw += w * bf2f(p.w);
    }
  }

  ax += __shfl_xor(ax, 32, 64);
  ay += __shfl_xor(ay, 32, 64);
  az += __shfl_xor(az, 32, 64);
  aw += __shfl_xor(aw, 32, 64);

  if (half == 0) {
    float di = dinv[node];
    float dii = di * di;
    ushort4 ps = rows[(size_t)node * 32 + l31];
    float4 bv = ((const float4*)bias)[l31];
    ax += dii * bf2f(ps.x) + bv.x;
    ay += dii * bf2f(ps.y) + bv.y;
    az += dii * bf2f(ps.z) + bv.z;
    aw += dii * bf2f(ps.w) + bv.w;
    if (resid != nullptr) {
      float4 r = ((const float4*)resid)[(size_t)node * 32 + l31];
      ax += r.x; ay += r.y; az += r.z; aw += r.w;
    }
    float4 o;
    o.x = ax > 0.0f ? ax : expm1f(ax);
    o.y = ay > 0.0f ? ay : expm1f(ay);
    o.z = az > 0.0f ? az : expm1f(az);
    o.w = aw > 0.0f ? aw : expm1f(aw);
    ((float4*)out)[(size_t)node * 32 + l31] = o;
  }
}

extern "C" void kernel_launch(void* const* d_in, const int* in_sizes, int n_in,
                              void* d_out, int out_size, void* d_ws, size_t ws_size,
                              hipStream_t stream) {
  const float* x  = (const float*)d_in[0];
  const int* eidx = (const int*)d_in[1];
  const float* W0 = (const float*)d_in[2];
  const float* b0 = (const float*)d_in[3];
  const float* W1 = (const float*)d_in[4];
  const float* b1 = (const float*)d_in[5];
  const float* W2 = (const float*)d_in[6];
  const float* b2 = (const float*)d_in[7];
  float* outp = (float*)d_out;

  const int N = in_sizes[0] / NFEAT;   // 100000
  const int E = in_sizes[1] / 2;       // 1600000 (divisible by 4)
  const int* src = eidx;
  const int* dst = eidx + E;
  const int NBUC = (N + BWID - 1) >> BSH;  // 196
  const int e4 = E / 4;

  // workspace layout (all chunk sizes 1KB-multiples)
  const size_t S1 = 401408;                   // > (N+1)*4
  const size_t SBK = 1024;                    // > (NBUC+1)*4
  const size_t SW = 32768;                    // 128*128*2
  const size_t SE = (size_t)E * 4;            // 6.4 MB packed edges
  const size_t SEB = (size_t)E * 8;           // 12.8 MB bucketed (dst,src)
  const size_t SH = (size_t)N * NFEAT * 2;    // 25.6 MB bf16 features
  const size_t SF = (size_t)N * NFEAT * 4;    // 51.2 MB fp32 features
  char* p = (char*)d_ws;
  float* dinv   = (float*)p;            p += S1;
  int*   rowp   = (int*)p;              p += S1;
  int*   bcnt   = (int*)p;              p += SBK;
  int*   boff   = (int*)p;              p += SBK;
  int*   gcur   = (int*)p;              p += SBK;
  unsigned short* Wt0 = (unsigned short*)p;  p += SW;
  unsigned short* Wt1 = (unsigned short*)p;  p += SW;
  unsigned short* Wt2 = (unsigned short*)p;  p += SW;
  unsigned int* colw = (unsigned int*)p; p += SE;
  unsigned long long* ebuf = (unsigned long long*)p; p += SEB;
  unsigned short* hWb = (unsigned short*)p;  p += SH;
  float* hA     = (float*)p;            p += SF;
  float* hB     = (float*)p;            p += SF;

  int gemm_blocks = (N + 63) / 64;        // 1563
  int cbk = (e4 + 1023) / 1024;           // 391 (4096 edges/block)
  int agg_blocks = (N + 3) / 4;

  // ---- prep + fused {gemm0, Pass A} ----
  wprep_kernel<<<192, 256, 0, stream>>>(W0, W1, W2, Wt0, Wt1, Wt2);
  hipMemsetAsync(bcnt, 0, (size_t)NBUC * 4, stream);
  fused_g0_hist_kernel<<<gemm_blocks + cbk, 256, 0, stream>>>(
      x, Wt0, hWb, N, gemm_blocks, (const int4*)dst, bcnt, e4, NBUC);

  // ---- bucketed CSR build ----
  scan_buckets_kernel<<<1, 256, 0, stream>>>(bcnt, boff, gcur, rowp,
                                             NBUC, N, E);
  bucket_scatter_kernel<<<cbk, 256, 0, stream>>>(
      (const int4*)src, (const int4*)dst, gcur, ebuf, e4);
  bucket_deg_kernel<<<NBUC, 256, 0, stream>>>(ebuf, boff, rowp, dinv, N);
  bucket_fill_kernel<<<NBUC, 256, 0, stream>>>(ebuf, boff, rowp, dinv,
                                               colw, N);

  // ---- layer 0 aggregate (gemm0 already done) ----
  aggregate_kernel<<<agg_blocks, 256, 0, stream>>>(hWb, rowp, colw, dinv,
                                                   b0, nullptr, hA, N);
  // ---- layer 1 ----
  gemm_mfma_kernel<<<gemm_blocks, 256, 0, stream>>>(hA, Wt1, hWb, N);
  aggregate_kernel<<<agg_blocks, 256, 0, stream>>>(hWb, rowp, colw, dinv,
                                                   b1, hA, hB, N);
  // ---- layer 2, write d_out ----
  gemm_mfma_kernel<<<gemm_blocks, 256, 0, stream>>>(hB, Wt2, hWb, N);
  aggregate_kernel<<<agg_blocks, 256, 0, stream>>>(hWb, rowp, colw, dinv,
                                                   b2, hB, outp, N);
}